// Round 6
// baseline (8125.529 us; speedup 1.0000x reference)
//
#include <hip/hip_runtime.h>
#include <stdint.h>
#include <math.h>

// ---------------------------------------------------------------------------
// ODE-LSTM on MI355X -- persistent RK4 round. f32 in/out.
// B=4096, OBS=256, H=1024, OUT=256, T=20 (19 RK4 steps).
//
// R13: fold the 76 stage GEMMs into ONE persistent dispatch (panel
// semaphores), fixing R10's disaster: NO acquire/invalidate anywhere.
//   - producer: fence(release,"agent") once per block-phase = buffer_wbl2
//     (writes back DIRTY lines only, RETAINS clean -> weights stay in L2)
//   - consumer A-loads: agent-scope (SC1, aux=16) global_load_lds -> bypass
//     possibly-stale local L2, read coherence point. Per-access coherence.
//   - B (weights) / u1b / Sb / Tb-rmw / P0-own-tile: block-private or
//     read-only -> plain cached accesses.
// Dependency is panel-local: phase p of block (bx,by) needs only the 16
// blocks (*,by) of phase p-1 -> cnt[by] >= 16*p gate (monotonic counter).
// Arithmetic & op order identical to R12 -> absmax must stay 0.00390625.
//
// Algebra (R11): u = h@W1+b1 carried, W21 = W2@W1, each stage ONE GEMM:
//   u2 = u1 + 0.5dt(t1_1@W21 + c2)         c2 = b2@W1
//   u3 = u1 + 0.5dt(t1_2@W21 + c2)
//   u4 = u1 +    dt(t1_3@W21 + c2)
//   u1'= u1 + (dt/6)(T@W21) + dt*c2        T = t1_1+2t1_2+2t1_3+t1_4
//   h_ode = h + S@W2 + (t19-t0)*b2         S = sum_s (dt_s/6) T_s
//
// ws (15 MiB): W21T[0,2) W2T[2,4) WiT[4,6.5) WoT[6.5,7) P0[7,15)
// d_out (36 MiB) overlays (all dead before the final writes):
//   u1b bf16 [0,8) | Tb bf16 [8,16) | P1 bf16 [16,24) | Sb bf16 [24,32)
//   W1T bf16 [32,34) (init only) | c2 f32 [34M,34M+4K) | cnt [34M+4K,+256)
// final: out f32 bytes [0,4M) | h_new [4,20M) | c_new [20,36M)
// ---------------------------------------------------------------------------

typedef __attribute__((ext_vector_type(8))) short short8;
typedef __attribute__((ext_vector_type(4))) float float4v;

#define BK 64

__device__ __forceinline__ float bf2f(unsigned short u) {
  union { unsigned int i; float f; } x;
  x.i = ((unsigned int)u) << 16;
  return x.f;
}
__device__ __forceinline__ unsigned short f2bf(float f) {
  union { float f; unsigned int i; } x;
  x.f = f;
  unsigned int r = x.i + 0x7fffu + ((x.i >> 16) & 1u);  // RNE
  return (unsigned short)(r >> 16);
}
__device__ __forceinline__ void load16(const void* g, void* l) {
  __builtin_amdgcn_global_load_lds(
      (__attribute__((address_space(1))) void*)g,
      (__attribute__((address_space(3))) void*)l, 16, 0, 0);
}
// Agent-scope (SC1) variant: bypasses the local XCD L2 so cross-XCD writes
// (pushed by producers' release/wbl2) are always visible. gfx940+ CPol:
// bit0=SC0, bit1=NT, bit4=SC1 -> aux=16.
__device__ __forceinline__ void load16_sc(const void* g, void* l) {
  __builtin_amdgcn_global_load_lds(
      (__attribute__((address_space(1))) void*)g,
      (__attribute__((address_space(3))) void*)l, 16, 0, 16);
}
__device__ __forceinline__ short8 packbf8(const float* p) {
  float4v lo = *(const float4v*)p, hi = *(const float4v*)(p + 4);
  short8 s;
  s[0] = (short)f2bf(lo[0]); s[1] = (short)f2bf(lo[1]);
  s[2] = (short)f2bf(lo[2]); s[3] = (short)f2bf(lo[3]);
  s[4] = (short)f2bf(hi[0]); s[5] = (short)f2bf(hi[1]);
  s[6] = (short)f2bf(hi[2]); s[7] = (short)f2bf(hi[3]);
  return s;
}
// a - b for two wave-uniform floats; avoids the gfx950 two-SGPR-source
// V_ADD_F32 constant-bus miscompile (R11) by forcing a through a VGPR.
__device__ __forceinline__ float vsub_uniform(float a, float b) {
  float av;
  asm("v_mov_b32 %0, %1" : "=v"(av) : "s"(a));
  return av - b;
}

// ---------------------------------------------------------------------------
// Persistent RK4: 76 phases (19 steps x 4 stage-GEMMs), 64x64 tiles,
// grid 1024 = exact residency (4 blocks/CU), panel semaphores.
// ---------------------------------------------------------------------------
__global__ __launch_bounds__(256, 4) void rk4_persist(
    const unsigned short* __restrict__ W21T,
    const float* __restrict__ tgrid,
    const float* __restrict__ c2,
    unsigned short* __restrict__ u1b,
    unsigned short* __restrict__ Tb,
    unsigned short* __restrict__ Sb,
    unsigned short* __restrict__ P0,
    unsigned short* __restrict__ P1,
    unsigned int* __restrict__ cnt) {
  __shared__ short8 AsV[2][512];  // 64 rows x 8 swizzled chunks x 16B
  __shared__ short8 BsV[2][512];

  const int t = threadIdx.x;
  const int lin = blockIdx.x;
  const int bx = lin & 15, by = lin >> 4;
  const int mBase = by * 64, nBase = bx * 64;
  const int wave = t >> 6, lane = t & 63;
  const int wr = wave >> 1, wc = wave & 1;
  const int q = lane >> 4, m16 = lane & 15;
  const int r0 = t >> 3;               // staging row 0..31 (also row+32)
  const int kcl = (t & 7) ^ (r0 & 7);  // swizzled k-chunk ((r0+32)&7==r0&7)

  const size_t aOff = (size_t)(mBase + r0) * 1024 + kcl * 8;
  const unsigned short* const A0 = P0 + aOff;  // sub 0,2
  const unsigned short* const A1 = P1 + aOff;  // sub 1
  const unsigned short* const A3 = Tb + aOff;  // sub 3
  const unsigned short* const bG = W21T + (size_t)(nBase + r0) * 1024 + kcl * 8;

  const int colBase = nBase + wc * 32 + m16;
  const int rowBase = mBase + wr * 32 + q * 4;

#pragma unroll 1
  for (int p = 0; p < 76; ++p) {
    const int sub = p & 3, step = p >> 2;

    if (p > 0) {
      // Gate: all 16 panel blocks finished phase p-1 (each +1 per phase).
      if (t == 0) {
        const unsigned int tgt = 16u * (unsigned int)p;
        while (__hip_atomic_load(cnt + by, __ATOMIC_RELAXED,
                                 __HIP_MEMORY_SCOPE_AGENT) < tgt)
          __builtin_amdgcn_s_sleep(2);
      }
      __syncthreads();  // releases waves; also fences LDS reuse vs stageT
    }

    const unsigned short* aU = (sub == 1) ? A1 : ((sub == 3) ? A3 : A0);

    float4v acc[2][2];
#pragma unroll
    for (int r = 0; r < 2; ++r)
#pragma unroll
      for (int c = 0; c < 2; ++c) acc[r][c] = (float4v){0.f, 0.f, 0.f, 0.f};

    auto stageT = [&](int buf, int k0) {
      load16_sc(aU + k0, &AsV[buf][t]);                 // A: agent-coherent
      load16_sc(aU + 32 * 1024 + k0, &AsV[buf][t + 256]);
      load16(bG + k0, &BsV[buf][t]);                    // B: plain cached
      load16(bG + 32 * 1024 + k0, &BsV[buf][t + 256]);
    };
    auto computeT = [&](int buf) {
#pragma unroll
      for (int kk = 0; kk < 2; ++kk) {
        const int kc = kk * 4 + q;
        short8 af[2], bfr[2];
#pragma unroll
        for (int r = 0; r < 2; ++r) {
          const int arow = wr * 32 + r * 16 + m16;
          af[r] = AsV[buf][arow * 8 + (kc ^ (arow & 7))];
          const int brow = wc * 32 + r * 16 + m16;
          bfr[r] = BsV[buf][brow * 8 + (kc ^ (brow & 7))];
        }
#pragma unroll
        for (int r = 0; r < 2; ++r)
#pragma unroll
          for (int c = 0; c < 2; ++c)
            acc[r][c] = __builtin_amdgcn_mfma_f32_16x16x32_bf16(
                af[r], bfr[c], acc[r][c], 0, 0, 0);
      }
    };

    // ---- 2-phase double-buffered K-loop, counted vmcnt(4) ----
    stageT(0, 0);
    int cur = 0;
#pragma unroll 1
    for (int k0 = BK; k0 < 1024; k0 += BK) {
      stageT(cur ^ 1, k0);
      asm volatile("s_waitcnt vmcnt(4)" ::: "memory");
      __builtin_amdgcn_sched_barrier(0);
      __builtin_amdgcn_s_barrier();
      __builtin_amdgcn_sched_barrier(0);
      computeT(cur);
      asm volatile("s_waitcnt lgkmcnt(0)" ::: "memory");
      __builtin_amdgcn_sched_barrier(0);
      __builtin_amdgcn_s_barrier();
      __builtin_amdgcn_sched_barrier(0);
      cur ^= 1;
    }
    asm volatile("s_waitcnt vmcnt(0)" ::: "memory");
    __builtin_amdgcn_sched_barrier(0);
    __builtin_amdgcn_s_barrier();
    __builtin_amdgcn_sched_barrier(0);
    computeT(cur);

    // ---- epilogue (identical math/order to R12's MODE 1..4) ----
    const float dtv = vsub_uniform(tgrid[step + 1], tgrid[step]);
#pragma unroll
    for (int r = 0; r < 2; ++r) {
#pragma unroll
      for (int c = 0; c < 2; ++c) {
        const int col = colBase + c * 16;
#pragma unroll
        for (int e = 0; e < 4; ++e) {
          const int row = rowBase + r * 16 + e;
          const size_t idx = (size_t)row * 1024 + col;
          const float v = acc[r][c][e];
          if (sub == 0) {        // G1
            const float u2 = bf2f(u1b[idx]) + 0.5f * dtv * (v + c2[col]);
            const float th = tanhf(u2);
            P1[idx] = f2bf(th);
            Tb[idx] = f2bf(bf2f(P0[idx]) + 2.f * th);   // P0[own] = t1_1
          } else if (sub == 1) { // G2
            const float u3 = bf2f(u1b[idx]) + 0.5f * dtv * (v + c2[col]);
            const float th = tanhf(u3);
            P0[idx] = f2bf(th);
            Tb[idx] = f2bf(bf2f(Tb[idx]) + 2.f * th);
          } else if (sub == 2) { // G3
            const float u4 = bf2f(u1b[idx]) + dtv * (v + c2[col]);
            Tb[idx] = f2bf(bf2f(Tb[idx]) + tanhf(u4));
          } else {               // G4
            const float u1n = bf2f(u1b[idx]) + (dtv * (1.f / 6.f)) * v + dtv * c2[col];
            u1b[idx] = f2bf(u1n);
            P0[idx] = f2bf(tanhf(u1n));
            const float sOld = (step == 0) ? 0.f : bf2f(Sb[idx]);
            Sb[idx] = f2bf(sOld + (dtv * (1.f / 6.f)) * bf2f(Tb[idx]));
          }
        }
      }
    }

    __syncthreads();  // per-wave vmcnt(0) drain -> all stores in local L2
    if (t == 0) {
      // release: wbl2 pushes DIRTY lines to coherence point, retains clean
      __builtin_amdgcn_fence(__ATOMIC_RELEASE, "agent");
      __hip_atomic_fetch_add(cnt + by, 1u, __ATOMIC_RELAXED,
                             __HIP_MEMORY_SCOPE_AGENT);
    }
  }
}

// ---------------------------------------------------------------------------
// C = A(MxK) * Bt(NxK bf16)^T, fused per-MODE epilogue. 64x64 tiles.
// Used for: 0 INIT (u1=h@W1+b1), 5 ZFIN (z=h+S@W2+(t19-t0)b2),
//           6 WT (W21T build), 7 OUT (out=h_new@Wo+bo).
// ---------------------------------------------------------------------------
template <int MODE, int ADT>
__global__ __launch_bounds__(256, 4) void gemm_ode(
    const void* Av, const unsigned short* __restrict__ Bt,
    int N, int K,
    const float* __restrict__ bias, const float* __restrict__ tgrid,
    int step, int first,
    unsigned short* __restrict__ u1b,
    unsigned short* __restrict__ Tb,
    unsigned short* __restrict__ Sb,
    unsigned short* __restrict__ t1dst,
    const void* aux,
    const float* __restrict__ c2,
    float* __restrict__ outF) {
  __shared__ short8 AsV[2][512];
  __shared__ short8 BsV[2][512];

  const int t = threadIdx.x;
  int bx = blockIdx.x, by = blockIdx.y;
  if (gridDim.x == 16 && gridDim.y == 64) {
    const int lin = bx + (by << 4);
    const int x = lin & 7, j = lin >> 3;
    bx = j & 15;
    by = (x << 3) | (j >> 4);
  }
  const int mBase = by * 64, nBase = bx * 64;
  const int wave = t >> 6, lane = t & 63;
  const int wr = wave >> 1, wc = wave & 1;
  const int q = lane >> 4, m16 = lane & 15;

  float4v acc[2][2];
#pragma unroll
  for (int r = 0; r < 2; ++r)
#pragma unroll
    for (int c = 0; c < 2; ++c) acc[r][c] = (float4v){0.f, 0.f, 0.f, 0.f};

  const int r0 = t >> 3;
  const int kcl = (t & 7) ^ (r0 & 7);
  const unsigned short* aU = (const unsigned short*)Av + (size_t)(mBase + r0) * K + kcl * 8;
  const float* aF = (const float*)Av + (size_t)(mBase + r0) * K + kcl * 8;
  const unsigned short* bG = Bt + (size_t)(nBase + r0) * K + kcl * 8;

  auto computeT = [&](int buf) {
#pragma unroll
    for (int kk = 0; kk < 2; ++kk) {
      const int kc = kk * 4 + q;
      short8 af[2], bfr[2];
#pragma unroll
      for (int r = 0; r < 2; ++r) {
        const int arow = wr * 32 + r * 16 + m16;
        af[r] = AsV[buf][arow * 8 + (kc ^ (arow & 7))];
        const int brow = wc * 32 + r * 16 + m16;
        bfr[r] = BsV[buf][brow * 8 + (kc ^ (brow & 7))];
      }
#pragma unroll
      for (int r = 0; r < 2; ++r)
#pragma unroll
        for (int c = 0; c < 2; ++c)
          acc[r][c] = __builtin_amdgcn_mfma_f32_16x16x32_bf16(af[r], bfr[c],
                                                              acc[r][c], 0, 0, 0);
    }
  };

  if constexpr (ADT == 1) {
    auto stageT = [&](int buf, int k0) {
      load16(aU + k0, &AsV[buf][t]);
      load16(aU + (size_t)32 * K + k0, &AsV[buf][t + 256]);
      load16(bG + k0, &BsV[buf][t]);
      load16(bG + (size_t)32 * K + k0, &BsV[buf][t + 256]);
    };
    stageT(0, 0);
    int cur = 0;
    for (int k0 = BK; k0 < K; k0 += BK) {
      stageT(cur ^ 1, k0);
      asm volatile("s_waitcnt vmcnt(4)" ::: "memory");
      __builtin_amdgcn_sched_barrier(0);
      __builtin_amdgcn_s_barrier();
      __builtin_amdgcn_sched_barrier(0);
      computeT(cur);
      asm volatile("s_waitcnt lgkmcnt(0)" ::: "memory");
      __builtin_amdgcn_sched_barrier(0);
      __builtin_amdgcn_s_barrier();
      __builtin_amdgcn_sched_barrier(0);
      cur ^= 1;
    }
    asm volatile("s_waitcnt vmcnt(0)" ::: "memory");
    __builtin_amdgcn_sched_barrier(0);
    __builtin_amdgcn_s_barrier();
    __builtin_amdgcn_sched_barrier(0);
    computeT(cur);
  } else {
    for (int k0 = 0; k0 < K; k0 += BK) {
      AsV[0][t] = packbf8(aF + k0);
      AsV[0][t + 256] = packbf8(aF + (size_t)32 * K + k0);
      load16(bG + k0, &BsV[0][t]);
      load16(bG + (size_t)32 * K + k0, &BsV[0][t + 256]);
      __builtin_amdgcn_s_waitcnt(0);
      __syncthreads();
      computeT(0);
      __syncthreads();
    }
  }

  float dtv = 0.f;
  if constexpr (MODE == 5) dtv = vsub_uniform(tgrid[step], tgrid[0]);

  const int colBase = nBase + wc * 32 + m16;
  const int rowBase = mBase + wr * 32 + q * 4;
#pragma unroll
  for (int r = 0; r < 2; ++r) {
#pragma unroll
    for (int c = 0; c < 2; ++c) {
      const int col = colBase + c * 16;
#pragma unroll
      for (int e = 0; e < 4; ++e) {
        const int row = rowBase + r * 16 + e;
        const size_t idx = (size_t)row * N + col;
        const float v = acc[r][c][e];
        if constexpr (MODE == 0) {
          const float u1 = v + bias[col];
          u1b[idx] = f2bf(u1);
          t1dst[idx] = f2bf(tanhf(u1));
        } else if constexpr (MODE == 5) {
          const float z = ((const float*)aux)[idx] + v + dtv * bias[col];
          t1dst[idx] = f2bf(z);
        } else if constexpr (MODE == 6) {
          t1dst[(size_t)col * 1024 + row] = f2bf(v);
        } else {  // MODE 7
          outF[idx] = v + bias[col];
        }
      }
    }
  }
}

// Fused gate + c_tilde dual GEMM, 64x64 tiles (4 blocks/CU):
// accG = [x|h]@WiT^T, accC = [x|z]@WiT^T; epilogue -> h_new, c_new.
__global__ __launch_bounds__(256, 4) void gemm_fused(
    const float* __restrict__ x, const float* __restrict__ h,
    const unsigned short* __restrict__ zB,
    const unsigned short* __restrict__ WiT,  // 1024 x 1280 bf16
    const float* __restrict__ bi, const float* __restrict__ c_in,
    float* __restrict__ hnewF, float* __restrict__ cnewF) {
  __shared__ short8 AsG[512];
  __shared__ short8 AsC[512];
  __shared__ short8 Bs[512];

  const int t = threadIdx.x;
  int bx = blockIdx.x, by = blockIdx.y;
  if (gridDim.x == 16 && gridDim.y == 64) {
    const int lin = bx + (by << 4);
    const int xc = lin & 7, j = lin >> 3;
    bx = j & 15;
    by = (xc << 3) | (j >> 4);
  }
  const int mBase = by * 64, nBase = bx * 64;
  const int wave = t >> 6, lane = t & 63;
  const int wr = wave >> 1, wc = wave & 1;
  const int q = lane >> 4, m16 = lane & 15;

  float4v accG[2][2], accC[2][2];
#pragma unroll
  for (int r = 0; r < 2; ++r)
#pragma unroll
    for (int c = 0; c < 2; ++c) {
      accG[r][c] = (float4v){0.f, 0.f, 0.f, 0.f};
      accC[r][c] = (float4v){0.f, 0.f, 0.f, 0.f};
    }

  const int r0 = t >> 3;
  const int kcl = (t & 7) ^ (r0 & 7);

  for (int k0 = 0; k0 < 1280; k0 += BK) {
    const bool isX = (k0 < 256);
#pragma unroll
    for (int i = 0; i < 2; ++i) {
      const int row = mBase + r0 + i * 32;
      short8 sg, sc;
      if (isX) {
        sg = packbf8(x + (size_t)row * 256 + k0 + kcl * 8);
        sc = sg;
      } else {
        const size_t off = (size_t)row * 1024 + (k0 - 256) + kcl * 8;
        sg = packbf8(h + off);
        sc = *(const short8*)(zB + off);
      }
      AsG[i * 256 + t] = sg;
      AsC[i * 256 + t] = sc;
      load16(WiT + (size_t)(nBase + r0 + i * 32) * 1280 + k0 + kcl * 8,
             &Bs[i * 256 + t]);
    }
    __builtin_amdgcn_s_waitcnt(0);
    __syncthreads();

#pragma unroll
    for (int kk = 0; kk < 2; ++kk) {
      const int kc = kk * 4 + q;
      short8 ag[2], ac[2], bfr[2];
#pragma unroll
      for (int r = 0; r < 2; ++r) {
        const int arow = wr * 32 + r * 16 + m16;
        ag[r] = AsG[arow * 8 + (kc ^ (arow & 7))];
        ac[r] = AsC[arow * 8 + (kc ^ (arow & 7))];
        const int brow = wc * 32 + r * 16 + m16;
        bfr[r] = Bs[brow * 8 + (kc ^ (brow & 7))];
      }
#pragma unroll
      for (int r = 0; r < 2; ++r)
#pragma unroll
        for (int c = 0; c < 2; ++c) {
          accG[r][c] = __builtin_amdgcn_mfma_f32_16x16x32_bf16(ag[r], bfr[c],
                                                               accG[r][c], 0, 0, 0);
          accC[r][c] = __builtin_amdgcn_mfma_f32_16x16x32_bf16(ac[r], bfr[c],
                                                               accC[r][c], 0, 0, 0);
        }
    }
    __syncthreads();
  }

  const int colBase = nBase + wc * 32 + m16;
  const int rowBase = mBase + wr * 32 + q * 4;
#pragma unroll
  for (int r = 0; r < 2; ++r) {
#pragma unroll
    for (int c = 0; c < 2; ++c) {
      const int col = colBase + c * 16;
      const float bv = bi[col];
#pragma unroll
      for (int e = 0; e < 4; ++e) {
        const int row = rowBase + r * 16 + e;
        const size_t idx = (size_t)row * 1024 + col;
        const float g = 1.f / (1.f + expf(-(accG[r][c][e] + bv)));
        const float ct = 1.f / (1.f + expf(-(accC[r][c][e] + bv)));
        const float cn = g * (c_in[idx] + ct);
        const float hn = g * tanhf(cn);
        hnewF[idx] = hn;
        cnewF[idx] = cn;
      }
    }
  }
}

// out[c][r] = bf16(in[r][c]); in f32 RxC. block (32,8), grid (C/32, R/32).
__global__ __launch_bounds__(256) void transpose_f32_bf16(
    const float* __restrict__ in, unsigned short* __restrict__ out,
    int R, int C) {
  __shared__ float tile[32][33];
  const int c0 = blockIdx.x * 32, r0 = blockIdx.y * 32;
  const int tx = threadIdx.x, ty = threadIdx.y;
#pragma unroll
  for (int i = 0; i < 32; i += 8)
    tile[ty + i][tx] = in[(size_t)(r0 + ty + i) * C + c0 + tx];
  __syncthreads();
#pragma unroll
  for (int i = 0; i < 32; i += 8)
    out[(size_t)(c0 + ty + i) * R + r0 + tx] = f2bf(tile[tx][ty + i]);
}

// c2[n] = sum_k b2[k]*W1[k,n]; also zero the 64 panel semaphores.
__global__ __launch_bounds__(256) void c2_gemv(
    const float* __restrict__ b2, const float* __restrict__ W1,
    float* __restrict__ c2v, unsigned int* __restrict__ cnt) {
  if (blockIdx.x == 0 && threadIdx.x < 64) cnt[threadIdx.x] = 0u;
  const int n = blockIdx.x * 256 + threadIdx.x;
  float a = 0.f;
  for (int k = 0; k < 1024; ++k) a += b2[k] * W1[(size_t)k * 1024 + n];
  c2v[n] = a;
}

extern "C" void kernel_launch(void* const* d_in, const int* in_sizes, int n_in,
                              void* d_out, int out_size, void* d_ws, size_t ws_size,
                              hipStream_t stream) {
  const float* x  = (const float*)d_in[0];   // 4096x256
  const float* h  = (const float*)d_in[1];   // 4096x1024
  const float* c  = (const float*)d_in[2];   // 4096x1024
  const float* t  = (const float*)d_in[3];   // 20
  const float* Wi = (const float*)d_in[4];   // 1280x1024
  const float* bi = (const float*)d_in[5];   // 1024
  const float* Wo = (const float*)d_in[6];   // 1024x256
  const float* bo = (const float*)d_in[7];   // 256
  const float* W1 = (const float*)d_in[8];   // 1024x1024
  const float* b1 = (const float*)d_in[9];   // 1024
  const float* W2 = (const float*)d_in[10];  // 1024x1024
  const float* b2 = (const float*)d_in[11];  // 1024

  const size_t MB = 1ull << 20;
  char* ws = (char*)d_ws;
  unsigned short* W21T = (unsigned short*)(ws);                      // [0,2M)
  unsigned short* W2T  = (unsigned short*)(ws + 2 * MB);             // [2,4M)
  unsigned short* WiT  = (unsigned short*)(ws + 4 * MB);             // [4,6.5M)
  unsigned short* WoT  = (unsigned short*)(ws + 6 * MB + 512 * 1024);// [6.5,7M)
  unsigned short* P0   = (unsigned short*)(ws + 7 * MB);             // [7,15M)

  // d_out overlays (all dead before the final output writes)
  float*          outF  = (float*)d_out;
  float*          hnewF = outF + 1048576;                            // [4,20M)
  float*          cnewF = outF + 5242880;                            // [20,36M)
  unsigned short* u1b   = (unsigned short*)d_out;                    // [0,8M)
  unsigned short* Tb    = (unsigned short*)((char*)d_out + 8 * MB);  // [8,16M)
  unsigned short* P1    = (unsigned short*)((char*)d_out + 16 * MB); // [16,24M)
  unsigned short* Sb    = (unsigned short*)((char*)d_out + 24 * MB); // [24,32M)
  unsigned short* W1T   = (unsigned short*)((char*)d_out + 32 * MB); // [32,34M)
  float*          c2v   = (float*)((char*)d_out + 34 * MB);          // 4 KB
  unsigned int*   cnt   = (unsigned int*)((char*)d_out + 34 * MB + 4096);

  const dim3 tb(32, 8), blk(256), g(16, 64);

  // weight prep
  transpose_f32_bf16<<<dim3(32, 32), tb, 0, stream>>>(W1, W1T, 1024, 1024);
  transpose_f32_bf16<<<dim3(32, 32), tb, 0, stream>>>(W2, W2T, 1024, 1024);
  transpose_f32_bf16<<<dim3(32, 40), tb, 0, stream>>>(Wi, WiT, 1280, 1024);
  transpose_f32_bf16<<<dim3(8, 32),  tb, 0, stream>>>(Wo, WoT, 1024, 256);
  c2_gemv<<<4, blk, 0, stream>>>(b2, W1, c2v, cnt);
  // W21T = (W2@W1)^T
  gemm_ode<6, 0><<<dim3(16, 16), blk, 0, stream>>>(
      W2, W1T, 1024, 1024, b1, t, 0, 0,
      nullptr, nullptr, nullptr, W21T, nullptr, nullptr, nullptr);
  // u1 = h@W1 + b1 ; t1_1 = tanh(u1) -> P0
  gemm_ode<0, 0><<<g, blk, 0, stream>>>(
      h, W1T, 1024, 1024, b1, t, 0, 0,
      u1b, nullptr, nullptr, P0, nullptr, nullptr, nullptr);

  // RK4: all 76 stage GEMMs in ONE persistent dispatch (panel semaphores)
  rk4_persist<<<1024, blk, 0, stream>>>(W21T, t, c2v, u1b, Tb, Sb, P0, P1, cnt);

  // z = h_ode = h + S@W2 + (t19-t0)*b2  -> bf16 into P0
  gemm_ode<5, 1><<<g, blk, 0, stream>>>(
      Sb, W2T, 1024, 1024, b2, t, 19, 0,
      nullptr, nullptr, nullptr, P0, h, nullptr, nullptr);

  // fused gate + c_tilde -> h_new, c_new (f32)
  gemm_fused<<<g, blk, 0, stream>>>(x, h, P0, WiT, bi, c, hnewF, cnewF);

  // out = h_new(f32) @ Wo + bo
  gemm_ode<7, 0><<<dim3(4, 64), blk, 0, stream>>>(
      hnewF, WoT, 256, 1024, bo, t, 0, 0,
      nullptr, nullptr, nullptr, nullptr, nullptr, nullptr, outF);
}

// Round 7
// 2359.732 us; speedup vs baseline: 3.4434x; 3.4434x over previous
//
#include <hip/hip_runtime.h>
#include <stdint.h>
#include <math.h>

// ---------------------------------------------------------------------------
// ODE-LSTM on MI355X -- R14: back to R12 multi-dispatch (persistent kernels
// failed twice: R10 invalidate storms, R13 SC1 coherent-read cost), with the
// stage GEMM re-tiled 64x64 -> 128x64 (4 waves, per-wave 64x32, acc[4][2]).
// Staging traffic (L2->LDS + LDS->reg) drops 25% (8 -> 6 B per output per
// K-step); K-accumulation order unchanged -> numerics bit-identical.
// grid (16,32) = 512 blocks = 2 blocks/CU (8 waves/CU), LDS 48 KB dbuf,
// counted vmcnt(6) pipeline, XCD stripe swizzle (3 MB/XCD working set).
//
// Algebra (R11): u = h@W1+b1 carried, W21 = W2@W1, each stage ONE GEMM:
//   u2 = u1 + 0.5dt(t1_1@W21 + c2)         c2 = b2@W1
//   u3 = u1 + 0.5dt(t1_2@W21 + c2)
//   u4 = u1 +    dt(t1_3@W21 + c2)
//   u1'= u1 + (dt/6)(T@W21) + dt*c2        T = t1_1+2t1_2+2t1_3+t1_4
//   h_ode = h + S@W2 + (t19-t0)*b2         S = sum_s (dt_s/6) T_s
//
// ws (15 MiB): W21T[0,2) W2T[2,4) WiT[4,6.5) WoT[6.5,7) P0[7,15)
// d_out (36+ MiB) overlays (all dead before the final writes):
//   u1b bf16 [0,8) | Tb bf16 [8,16) | P1 bf16 [16,24) | Sb bf16 [24,32)
//   W1T bf16 [32,34) (init only) | c2 f32 [34M,34M+4K)
// final: out f32 bytes [0,4M) | h_new [4,20M) | c_new [20,36M)
// ---------------------------------------------------------------------------

typedef __attribute__((ext_vector_type(8))) short short8;
typedef __attribute__((ext_vector_type(4))) float float4v;

#define BK 64

__device__ __forceinline__ float bf2f(unsigned short u) {
  union { unsigned int i; float f; } x;
  x.i = ((unsigned int)u) << 16;
  return x.f;
}
__device__ __forceinline__ unsigned short f2bf(float f) {
  union { float f; unsigned int i; } x;
  x.f = f;
  unsigned int r = x.i + 0x7fffu + ((x.i >> 16) & 1u);  // RNE
  return (unsigned short)(r >> 16);
}
__device__ __forceinline__ void load16(const void* g, void* l) {
  __builtin_amdgcn_global_load_lds(
      (__attribute__((address_space(1))) void*)g,
      (__attribute__((address_space(3))) void*)l, 16, 0, 0);
}
__device__ __forceinline__ short8 packbf8(const float* p) {
  float4v lo = *(const float4v*)p, hi = *(const float4v*)(p + 4);
  short8 s;
  s[0] = (short)f2bf(lo[0]); s[1] = (short)f2bf(lo[1]);
  s[2] = (short)f2bf(lo[2]); s[3] = (short)f2bf(lo[3]);
  s[4] = (short)f2bf(hi[0]); s[5] = (short)f2bf(hi[1]);
  s[6] = (short)f2bf(hi[2]); s[7] = (short)f2bf(hi[3]);
  return s;
}
// a - b for two wave-uniform floats; avoids the gfx950 two-SGPR-source
// V_ADD_F32 constant-bus miscompile (R11) by forcing a through a VGPR.
__device__ __forceinline__ float vsub_uniform(float a, float b) {
  float av;
  asm("v_mov_b32 %0, %1" : "=v"(av) : "s"(a));
  return av - b;
}

// ---------------------------------------------------------------------------
// Stage GEMM: C = A(4096xK=1024 bf16) * W21T(1024x1024 bf16)^T, 128x64 tile,
// 256 threads (4 waves 2x2; per-wave 64x32 out, acc[4][2]). 2-phase
// double-buffered K-loop, counted vmcnt(6). SUB = RK4 stage epilogue 0..3.
// grid (16,32) = 512 blocks = 2 blocks/CU. Numerics identical to R12.
// ---------------------------------------------------------------------------
template <int SUB>
__global__ __launch_bounds__(256, 2) void gemm_stage(
    const unsigned short* __restrict__ Av,
    const unsigned short* __restrict__ W21T,
    const float* __restrict__ tgrid, int step,
    const float* __restrict__ c2,
    unsigned short* __restrict__ u1b,
    unsigned short* __restrict__ Tb,
    unsigned short* __restrict__ Sb,
    unsigned short* __restrict__ P0,
    unsigned short* __restrict__ P1) {
  __shared__ short8 AsV[2][1024];  // 128 rows x 8 swizzled chunks = 16 KB/buf
  __shared__ short8 BsV[2][512];   // 64 rows  x 8 swizzled chunks =  8 KB/buf

  const int t = threadIdx.x;
  int bx = blockIdx.x, by = blockIdx.y;
  // Bijective XCD stripe swizzle for (16,32): XCD x = lin&7 owns by in
  // [x*4, x*4+4). Working set/XCD: A 4x256KB = 1MB + B 2MB = 3MB < 4MB L2.
  {
    const int lin = bx + (by << 4);
    const int x = lin & 7, j = lin >> 3;  // j in 0..63
    bx = j & 15;
    by = (x << 2) | (j >> 4);
  }
  const int mBase = by * 128, nBase = bx * 64;
  const int wave = t >> 6, lane = t & 63;
  const int wr = wave >> 1, wc = wave & 1;
  const int q = lane >> 4, m16 = lane & 15;
  const int r0 = t >> 3;               // staging row 0..31 (rows +32,+64,+96)
  const int kcl = (t & 7) ^ (r0 & 7);  // swizzled k-chunk ((r0+32k)&7==r0&7)

  const unsigned short* aU = Av + (size_t)(mBase + r0) * 1024 + kcl * 8;
  const unsigned short* bG = W21T + (size_t)(nBase + r0) * 1024 + kcl * 8;

  float4v acc[4][2];
#pragma unroll
  for (int r = 0; r < 4; ++r)
#pragma unroll
    for (int c = 0; c < 2; ++c) acc[r][c] = (float4v){0.f, 0.f, 0.f, 0.f};

  auto stageT = [&](int buf, int k0) {
    load16(aU + k0, &AsV[buf][t]);
    load16(aU + 32 * 1024 + k0, &AsV[buf][t + 256]);
    load16(aU + 64 * 1024 + k0, &AsV[buf][t + 512]);
    load16(aU + 96 * 1024 + k0, &AsV[buf][t + 768]);
    load16(bG + k0, &BsV[buf][t]);
    load16(bG + 32 * 1024 + k0, &BsV[buf][t + 256]);
  };
  auto computeT = [&](int buf) {
#pragma unroll
    for (int kk = 0; kk < 2; ++kk) {
      const int kc = kk * 4 + q;
      short8 af[4], bfr[2];
#pragma unroll
      for (int r = 0; r < 4; ++r) {
        const int arow = wr * 64 + r * 16 + m16;
        af[r] = AsV[buf][arow * 8 + (kc ^ (arow & 7))];
      }
#pragma unroll
      for (int c = 0; c < 2; ++c) {
        const int brow = wc * 32 + c * 16 + m16;
        bfr[c] = BsV[buf][brow * 8 + (kc ^ (brow & 7))];
      }
#pragma unroll
      for (int r = 0; r < 4; ++r)
#pragma unroll
        for (int c = 0; c < 2; ++c)
          acc[r][c] = __builtin_amdgcn_mfma_f32_16x16x32_bf16(
              af[r], bfr[c], acc[r][c], 0, 0, 0);
    }
  };

  // ---- 2-phase double-buffered K-loop, counted vmcnt(6) ----
  stageT(0, 0);
  int cur = 0;
#pragma unroll 1
  for (int k0 = BK; k0 < 1024; k0 += BK) {
    stageT(cur ^ 1, k0);  // next tile's 6 loads join the queue
    asm volatile("s_waitcnt vmcnt(6)" ::: "memory");
    __builtin_amdgcn_sched_barrier(0);
    __builtin_amdgcn_s_barrier();
    __builtin_amdgcn_sched_barrier(0);
    computeT(cur);
    asm volatile("s_waitcnt lgkmcnt(0)" ::: "memory");
    __builtin_amdgcn_sched_barrier(0);
    __builtin_amdgcn_s_barrier();
    __builtin_amdgcn_sched_barrier(0);
    cur ^= 1;
  }
  asm volatile("s_waitcnt vmcnt(0)" ::: "memory");
  __builtin_amdgcn_sched_barrier(0);
  __builtin_amdgcn_s_barrier();
  __builtin_amdgcn_sched_barrier(0);
  computeT(cur);

  // ---- epilogue (identical math/order to R12 MODE 1..4) ----
  const float dtv = vsub_uniform(tgrid[step + 1], tgrid[step]);
  const int colBase = nBase + wc * 32 + m16;
  const int rowBase = mBase + wr * 64 + q * 4;
#pragma unroll
  for (int r = 0; r < 4; ++r) {
#pragma unroll
    for (int c = 0; c < 2; ++c) {
      const int col = colBase + c * 16;
#pragma unroll
      for (int e = 0; e < 4; ++e) {
        const int row = rowBase + r * 16 + e;
        const size_t idx = (size_t)row * 1024 + col;
        const float v = acc[r][c][e];
        if constexpr (SUB == 0) {        // G1
          const float u2 = bf2f(u1b[idx]) + 0.5f * dtv * (v + c2[col]);
          const float th = tanhf(u2);
          P1[idx] = f2bf(th);
          Tb[idx] = f2bf(bf2f(P0[idx]) + 2.f * th);  // P0[own] = t1_1
        } else if constexpr (SUB == 1) { // G2
          const float u3 = bf2f(u1b[idx]) + 0.5f * dtv * (v + c2[col]);
          const float th = tanhf(u3);
          P0[idx] = f2bf(th);
          Tb[idx] = f2bf(bf2f(Tb[idx]) + 2.f * th);
        } else if constexpr (SUB == 2) { // G3
          const float u4 = bf2f(u1b[idx]) + dtv * (v + c2[col]);
          Tb[idx] = f2bf(bf2f(Tb[idx]) + tanhf(u4));
        } else {                         // G4
          const float u1n = bf2f(u1b[idx]) + (dtv * (1.f / 6.f)) * v + dtv * c2[col];
          u1b[idx] = f2bf(u1n);
          P0[idx] = f2bf(tanhf(u1n));
          const float sOld = (step == 0) ? 0.f : bf2f(Sb[idx]);
          Sb[idx] = f2bf(sOld + (dtv * (1.f / 6.f)) * bf2f(Tb[idx]));
        }
      }
    }
  }
}

// ---------------------------------------------------------------------------
// C = A(MxK) * Bt(NxK bf16)^T, fused per-MODE epilogue. 64x64 tiles.
// MODE: 0 INIT (u1=h@W1+b1), 5 ZFIN (z=h+S@W2+(t19-t0)b2),
//       6 WT (W21T build), 7 OUT (out=h_new@Wo+bo).
// ---------------------------------------------------------------------------
template <int MODE, int ADT>
__global__ __launch_bounds__(256, 4) void gemm_ode(
    const void* Av, const unsigned short* __restrict__ Bt,
    int N, int K,
    const float* __restrict__ bias, const float* __restrict__ tgrid,
    int step, int first,
    unsigned short* __restrict__ u1b,
    unsigned short* __restrict__ Tb,
    unsigned short* __restrict__ Sb,
    unsigned short* __restrict__ t1dst,
    const void* aux,
    const float* __restrict__ c2,
    float* __restrict__ outF) {
  __shared__ short8 AsV[2][512];
  __shared__ short8 BsV[2][512];

  const int t = threadIdx.x;
  int bx = blockIdx.x, by = blockIdx.y;
  if (gridDim.x == 16 && gridDim.y == 64) {
    const int lin = bx + (by << 4);
    const int x = lin & 7, j = lin >> 3;
    bx = j & 15;
    by = (x << 3) | (j >> 4);
  }
  const int mBase = by * 64, nBase = bx * 64;
  const int wave = t >> 6, lane = t & 63;
  const int wr = wave >> 1, wc = wave & 1;
  const int q = lane >> 4, m16 = lane & 15;

  float4v acc[2][2];
#pragma unroll
  for (int r = 0; r < 2; ++r)
#pragma unroll
    for (int c = 0; c < 2; ++c) acc[r][c] = (float4v){0.f, 0.f, 0.f, 0.f};

  const int r0 = t >> 3;
  const int kcl = (t & 7) ^ (r0 & 7);
  const unsigned short* aU = (const unsigned short*)Av + (size_t)(mBase + r0) * K + kcl * 8;
  const float* aF = (const float*)Av + (size_t)(mBase + r0) * K + kcl * 8;
  const unsigned short* bG = Bt + (size_t)(nBase + r0) * K + kcl * 8;

  auto computeT = [&](int buf) {
#pragma unroll
    for (int kk = 0; kk < 2; ++kk) {
      const int kc = kk * 4 + q;
      short8 af[2], bfr[2];
#pragma unroll
      for (int r = 0; r < 2; ++r) {
        const int arow = wr * 32 + r * 16 + m16;
        af[r] = AsV[buf][arow * 8 + (kc ^ (arow & 7))];
        const int brow = wc * 32 + r * 16 + m16;
        bfr[r] = BsV[buf][brow * 8 + (kc ^ (brow & 7))];
      }
#pragma unroll
      for (int r = 0; r < 2; ++r)
#pragma unroll
        for (int c = 0; c < 2; ++c)
          acc[r][c] = __builtin_amdgcn_mfma_f32_16x16x32_bf16(af[r], bfr[c],
                                                              acc[r][c], 0, 0, 0);
    }
  };

  if constexpr (ADT == 1) {
    auto stageT = [&](int buf, int k0) {
      load16(aU + k0, &AsV[buf][t]);
      load16(aU + (size_t)32 * K + k0, &AsV[buf][t + 256]);
      load16(bG + k0, &BsV[buf][t]);
      load16(bG + (size_t)32 * K + k0, &BsV[buf][t + 256]);
    };
    stageT(0, 0);
    int cur = 0;
    for (int k0 = BK; k0 < K; k0 += BK) {
      stageT(cur ^ 1, k0);
      asm volatile("s_waitcnt vmcnt(4)" ::: "memory");
      __builtin_amdgcn_sched_barrier(0);
      __builtin_amdgcn_s_barrier();
      __builtin_amdgcn_sched_barrier(0);
      computeT(cur);
      asm volatile("s_waitcnt lgkmcnt(0)" ::: "memory");
      __builtin_amdgcn_sched_barrier(0);
      __builtin_amdgcn_s_barrier();
      __builtin_amdgcn_sched_barrier(0);
      cur ^= 1;
    }
    asm volatile("s_waitcnt vmcnt(0)" ::: "memory");
    __builtin_amdgcn_sched_barrier(0);
    __builtin_amdgcn_s_barrier();
    __builtin_amdgcn_sched_barrier(0);
    computeT(cur);
  } else {
    for (int k0 = 0; k0 < K; k0 += BK) {
      AsV[0][t] = packbf8(aF + k0);
      AsV[0][t + 256] = packbf8(aF + (size_t)32 * K + k0);
      load16(bG + k0, &BsV[0][t]);
      load16(bG + (size_t)32 * K + k0, &BsV[0][t + 256]);
      __builtin_amdgcn_s_waitcnt(0);
      __syncthreads();
      computeT(0);
      __syncthreads();
    }
  }

  float dtv = 0.f;
  if constexpr (MODE == 5) dtv = vsub_uniform(tgrid[step], tgrid[0]);

  const int colBase = nBase + wc * 32 + m16;
  const int rowBase = mBase + wr * 32 + q * 4;
#pragma unroll
  for (int r = 0; r < 2; ++r) {
#pragma unroll
    for (int c = 0; c < 2; ++c) {
      const int col = colBase + c * 16;
#pragma unroll
      for (int e = 0; e < 4; ++e) {
        const int row = rowBase + r * 16 + e;
        const size_t idx = (size_t)row * N + col;
        const float v = acc[r][c][e];
        if constexpr (MODE == 0) {
          const float u1 = v + bias[col];
          u1b[idx] = f2bf(u1);
          t1dst[idx] = f2bf(tanhf(u1));
        } else if constexpr (MODE == 5) {
          const float z = ((const float*)aux)[idx] + v + dtv * bias[col];
          t1dst[idx] = f2bf(z);
        } else if constexpr (MODE == 6) {
          t1dst[(size_t)col * 1024 + row] = f2bf(v);
        } else {  // MODE 7
          outF[idx] = v + bias[col];
        }
      }
    }
  }
}

// Fused gate + c_tilde dual GEMM, 64x64 tiles (4 blocks/CU):
// accG = [x|h]@WiT^T, accC = [x|z]@WiT^T; epilogue -> h_new, c_new.
__global__ __launch_bounds__(256, 4) void gemm_fused(
    const float* __restrict__ x, const float* __restrict__ h,
    const unsigned short* __restrict__ zB,
    const unsigned short* __restrict__ WiT,  // 1024 x 1280 bf16
    const float* __restrict__ bi, const float* __restrict__ c_in,
    float* __restrict__ hnewF, float* __restrict__ cnewF) {
  __shared__ short8 AsG[512];
  __shared__ short8 AsC[512];
  __shared__ short8 Bs[512];

  const int t = threadIdx.x;
  int bx = blockIdx.x, by = blockIdx.y;
  if (gridDim.x == 16 && gridDim.y == 64) {
    const int lin = bx + (by << 4);
    const int xc = lin & 7, j = lin >> 3;
    bx = j & 15;
    by = (xc << 3) | (j >> 4);
  }
  const int mBase = by * 64, nBase = bx * 64;
  const int wave = t >> 6, lane = t & 63;
  const int wr = wave >> 1, wc = wave & 1;
  const int q = lane >> 4, m16 = lane & 15;

  float4v accG[2][2], accC[2][2];
#pragma unroll
  for (int r = 0; r < 2; ++r)
#pragma unroll
    for (int c = 0; c < 2; ++c) {
      accG[r][c] = (float4v){0.f, 0.f, 0.f, 0.f};
      accC[r][c] = (float4v){0.f, 0.f, 0.f, 0.f};
    }

  const int r0 = t >> 3;
  const int kcl = (t & 7) ^ (r0 & 7);

  for (int k0 = 0; k0 < 1280; k0 += BK) {
    const bool isX = (k0 < 256);
#pragma unroll
    for (int i = 0; i < 2; ++i) {
      const int row = mBase + r0 + i * 32;
      short8 sg, sc;
      if (isX) {
        sg = packbf8(x + (size_t)row * 256 + k0 + kcl * 8);
        sc = sg;
      } else {
        const size_t off = (size_t)row * 1024 + (k0 - 256) + kcl * 8;
        sg = packbf8(h + off);
        sc = *(const short8*)(zB + off);
      }
      AsG[i * 256 + t] = sg;
      AsC[i * 256 + t] = sc;
      load16(WiT + (size_t)(nBase + r0 + i * 32) * 1280 + k0 + kcl * 8,
             &Bs[i * 256 + t]);
    }
    __builtin_amdgcn_s_waitcnt(0);
    __syncthreads();

#pragma unroll
    for (int kk = 0; kk < 2; ++kk) {
      const int kc = kk * 4 + q;
      short8 ag[2], ac[2], bfr[2];
#pragma unroll
      for (int r = 0; r < 2; ++r) {
        const int arow = wr * 32 + r * 16 + m16;
        ag[r] = AsG[arow * 8 + (kc ^ (arow & 7))];
        ac[r] = AsC[arow * 8 + (kc ^ (arow & 7))];
        const int brow = wc * 32 + r * 16 + m16;
        bfr[r] = Bs[brow * 8 + (kc ^ (brow & 7))];
      }
#pragma unroll
      for (int r = 0; r < 2; ++r)
#pragma unroll
        for (int c = 0; c < 2; ++c) {
          accG[r][c] = __builtin_amdgcn_mfma_f32_16x16x32_bf16(ag[r], bfr[c],
                                                               accG[r][c], 0, 0, 0);
          accC[r][c] = __builtin_amdgcn_mfma_f32_16x16x32_bf16(ac[r], bfr[c],
                                                               accC[r][c], 0, 0, 0);
        }
    }
    __syncthreads();
  }

  const int colBase = nBase + wc * 32 + m16;
  const int rowBase = mBase + wr * 32 + q * 4;
#pragma unroll
  for (int r = 0; r < 2; ++r) {
#pragma unroll
    for (int c = 0; c < 2; ++c) {
      const int col = colBase + c * 16;
      const float bv = bi[col];
#pragma unroll
      for (int e = 0; e < 4; ++e) {
        const int row = rowBase + r * 16 + e;
        const size_t idx = (size_t)row * 1024 + col;
        const float g = 1.f / (1.f + expf(-(accG[r][c][e] + bv)));
        const float ct = 1.f / (1.f + expf(-(accC[r][c][e] + bv)));
        const float cn = g * (c_in[idx] + ct);
        const float hn = g * tanhf(cn);
        hnewF[idx] = hn;
        cnewF[idx] = cn;
      }
    }
  }
}

// out[c][r] = bf16(in[r][c]); in f32 RxC. block (32,8), grid (C/32, R/32).
__global__ __launch_bounds__(256) void transpose_f32_bf16(
    const float* __restrict__ in, unsigned short* __restrict__ out,
    int R, int C) {
  __shared__ float tile[32][33];
  const int c0 = blockIdx.x * 32, r0 = blockIdx.y * 32;
  const int tx = threadIdx.x, ty = threadIdx.y;
#pragma unroll
  for (int i = 0; i < 32; i += 8)
    tile[ty + i][tx] = in[(size_t)(r0 + ty + i) * C + c0 + tx];
  __syncthreads();
#pragma unroll
  for (int i = 0; i < 32; i += 8)
    out[(size_t)(c0 + ty + i) * R + r0 + tx] = f2bf(tile[tx][ty + i]);
}

// c2[n] = sum_k b2[k]*W1[k,n]  (one-off, tiny)
__global__ __launch_bounds__(256) void c2_gemv(
    const float* __restrict__ b2, const float* __restrict__ W1,
    float* __restrict__ c2v) {
  const int n = blockIdx.x * 256 + threadIdx.x;
  float a = 0.f;
  for (int k = 0; k < 1024; ++k) a += b2[k] * W1[(size_t)k * 1024 + n];
  c2v[n] = a;
}

extern "C" void kernel_launch(void* const* d_in, const int* in_sizes, int n_in,
                              void* d_out, int out_size, void* d_ws, size_t ws_size,
                              hipStream_t stream) {
  const float* x  = (const float*)d_in[0];   // 4096x256
  const float* h  = (const float*)d_in[1];   // 4096x1024
  const float* c  = (const float*)d_in[2];   // 4096x1024
  const float* t  = (const float*)d_in[3];   // 20
  const float* Wi = (const float*)d_in[4];   // 1280x1024
  const float* bi = (const float*)d_in[5];   // 1024
  const float* Wo = (const float*)d_in[6];   // 1024x256
  const float* bo = (const float*)d_in[7];   // 256
  const float* W1 = (const float*)d_in[8];   // 1024x1024
  const float* b1 = (const float*)d_in[9];   // 1024
  const float* W2 = (const float*)d_in[10];  // 1024x1024
  const float* b2 = (const float*)d_in[11];  // 1024

  const size_t MB = 1ull << 20;
  char* ws = (char*)d_ws;
  unsigned short* W21T = (unsigned short*)(ws);                      // [0,2M)
  unsigned short* W2T  = (unsigned short*)(ws + 2 * MB);             // [2,4M)
  unsigned short* WiT  = (unsigned short*)(ws + 4 * MB);             // [4,6.5M)
  unsigned short* WoT  = (unsigned short*)(ws + 6 * MB + 512 * 1024);// [6.5,7M)
  unsigned short* P0   = (unsigned short*)(ws + 7 * MB);             // [7,15M)

  // d_out overlays (all dead before the final output writes)
  float*          outF  = (float*)d_out;
  float*          hnewF = outF + 1048576;                            // [4,20M)
  float*          cnewF = outF + 5242880;                            // [20,36M)
  unsigned short* u1b   = (unsigned short*)d_out;                    // [0,8M)
  unsigned short* Tb    = (unsigned short*)((char*)d_out + 8 * MB);  // [8,16M)
  unsigned short* P1    = (unsigned short*)((char*)d_out + 16 * MB); // [16,24M)
  unsigned short* Sb    = (unsigned short*)((char*)d_out + 24 * MB); // [24,32M)
  unsigned short* W1T   = (unsigned short*)((char*)d_out + 32 * MB); // [32,34M)
  float*          c2v   = (float*)((char*)d_out + 34 * MB);          // 4 KB

  const dim3 tb(32, 8), blk(256), g(16, 64), gs(16, 32);

  // weight prep
  transpose_f32_bf16<<<dim3(32, 32), tb, 0, stream>>>(W1, W1T, 1024, 1024);
  transpose_f32_bf16<<<dim3(32, 32), tb, 0, stream>>>(W2, W2T, 1024, 1024);
  transpose_f32_bf16<<<dim3(32, 40), tb, 0, stream>>>(Wi, WiT, 1280, 1024);
  transpose_f32_bf16<<<dim3(8, 32),  tb, 0, stream>>>(Wo, WoT, 1024, 256);
  c2_gemv<<<4, blk, 0, stream>>>(b2, W1, c2v);
  // W21T = (W2@W1)^T
  gemm_ode<6, 0><<<dim3(16, 16), blk, 0, stream>>>(
      W2, W1T, 1024, 1024, b1, t, 0, 0,
      nullptr, nullptr, nullptr, W21T, nullptr, nullptr, nullptr);
  // u1 = h@W1 + b1 ; t1_1 = tanh(u1) -> P0
  gemm_ode<0, 0><<<g, blk, 0, stream>>>(
      h, W1T, 1024, 1024, b1, t, 0, 0,
      u1b, nullptr, nullptr, P0, nullptr, nullptr, nullptr);

  // RK4: 19 steps x 4 single GEMMs (128x64 tiles, all vs W21T)
  for (int s = 0; s < 19; ++s) {
    gemm_stage<0><<<gs, blk, 0, stream>>>(P0, W21T, t, s, c2v, u1b, Tb, Sb, P0, P1);
    gemm_stage<1><<<gs, blk, 0, stream>>>(P1, W21T, t, s, c2v, u1b, Tb, Sb, P0, P1);
    gemm_stage<2><<<gs, blk, 0, stream>>>(P0, W21T, t, s, c2v, u1b, Tb, Sb, P0, P1);
    gemm_stage<3><<<gs, blk, 0, stream>>>(Tb, W21T, t, s, c2v, u1b, Tb, Sb, P0, P1);
  }

  // z = h_ode = h + S@W2 + (t19-t0)*b2  -> bf16 into P0
  gemm_ode<5, 1><<<g, blk, 0, stream>>>(
      Sb, W2T, 1024, 1024, b2, t, 19, 0,
      nullptr, nullptr, nullptr, P0, h, nullptr, nullptr);

  // fused gate + c_tilde -> h_new, c_new (f32)
  gemm_fused<<<g, blk, 0, stream>>>(x, h, P0, WiT, bi, c, hnewF, cnewF);

  // out = h_new(f32) @ Wo + bo
  gemm_ode<7, 0><<<dim3(4, 64), blk, 0, stream>>>(
      hnewF, WoT, 256, 1024, bo, t, 0, 0,
      nullptr, nullptr, nullptr, nullptr, nullptr, nullptr, outF);
}

// Round 8
// 1729.997 us; speedup vs baseline: 4.6968x; 1.3640x over previous
//
#include <hip/hip_runtime.h>
#include <stdint.h>
#include <math.h>

// ---------------------------------------------------------------------------
// ODE-LSTM on MI355X -- R15. f32 in/out.
// B=4096, OBS=256, H=1024, OUT=256, T=20 (19 RK4 steps).
//
// R15 = R12 revert (stage GEMMs: 64x64, 4 blocks/CU -- R14's 128x64 tile
// regressed 18->27 us/стage by dropping occupancy; 4 blk/CU is a hard
// requirement for this latency-bound skinny-N GEMM) + gemm_fused rebuilt
// with the counted-vmcnt pipeline: A-side (x/h f32 + zB bf16) prefetched
// into registers one tile ahead, Bs (WiT) double-buffered via
// global_load_lds, vmcnt(8) counted waits. LDS 32 KB -> still 4 blocks/CU.
// Numerics bit-identical to R12 (same rounding, same MFMA order).
//
// Algebra (R11): u = h@W1+b1 carried, W21 = W2@W1, each stage ONE GEMM:
//   u2 = u1 + 0.5dt(t1_1@W21 + c2)         c2 = b2@W1
//   u3 = u1 + 0.5dt(t1_2@W21 + c2)
//   u4 = u1 +    dt(t1_3@W21 + c2)
//   u1'= u1 + (dt/6)(T@W21) + dt*c2        T = t1_1+2t1_2+2t1_3+t1_4
//   h_ode = h + S@W2 + (t19-t0)*b2         S = sum_s (dt_s/6) T_s
//
// ws (15 MiB): W21T[0,2) W2T[2,4) WiT[4,6.5) WoT[6.5,7) P0[7,15)
// d_out overlays (all dead before the final writes):
//   u1b bf16 [0,8) | Tb bf16 [8,16) | P1 bf16 [16,24) | Sb bf16 [24,32)
//   W1T bf16 [32,34) (init only) | c2 f32 [34M,34M+4K)
// final: out f32 bytes [0,4M) | h_new [4,20M) | c_new [20,36M)
// ---------------------------------------------------------------------------

typedef __attribute__((ext_vector_type(8))) short short8;
typedef __attribute__((ext_vector_type(4))) float float4v;

#define BK 64

__device__ __forceinline__ float bf2f(unsigned short u) {
  union { unsigned int i; float f; } x;
  x.i = ((unsigned int)u) << 16;
  return x.f;
}
__device__ __forceinline__ unsigned short f2bf(float f) {
  union { float f; unsigned int i; } x;
  x.f = f;
  unsigned int r = x.i + 0x7fffu + ((x.i >> 16) & 1u);  // RNE
  return (unsigned short)(r >> 16);
}
__device__ __forceinline__ void load16(const void* g, void* l) {
  __builtin_amdgcn_global_load_lds(
      (__attribute__((address_space(1))) void*)g,
      (__attribute__((address_space(3))) void*)l, 16, 0, 0);
}
__device__ __forceinline__ short8 packbf8(const float* p) {
  float4v lo = *(const float4v*)p, hi = *(const float4v*)(p + 4);
  short8 s;
  s[0] = (short)f2bf(lo[0]); s[1] = (short)f2bf(lo[1]);
  s[2] = (short)f2bf(lo[2]); s[3] = (short)f2bf(lo[3]);
  s[4] = (short)f2bf(hi[0]); s[5] = (short)f2bf(hi[1]);
  s[6] = (short)f2bf(hi[2]); s[7] = (short)f2bf(hi[3]);
  return s;
}
__device__ __forceinline__ short8 pack2(float4v lo, float4v hi) {
  short8 s;
  s[0] = (short)f2bf(lo[0]); s[1] = (short)f2bf(lo[1]);
  s[2] = (short)f2bf(lo[2]); s[3] = (short)f2bf(lo[3]);
  s[4] = (short)f2bf(hi[0]); s[5] = (short)f2bf(hi[1]);
  s[6] = (short)f2bf(hi[2]); s[7] = (short)f2bf(hi[3]);
  return s;
}
// a - b for two wave-uniform floats; avoids the gfx950 two-SGPR-source
// V_ADD_F32 constant-bus miscompile (R11) by forcing a through a VGPR.
__device__ __forceinline__ float vsub_uniform(float a, float b) {
  float av;
  asm("v_mov_b32 %0, %1" : "=v"(av) : "s"(a));
  return av - b;
}

// ---------------------------------------------------------------------------
// C = A(MxK row-major) * Bt(NxK bf16 row-major)^T, fused per-MODE epilogue.
// 64x64 tiles, 256 threads (4 waves 2x2, 32x32 out each, acc 2x2).
// ADT: 1 = A bf16 (global_load_lds, 2-phase counted-vmcnt pipeline),
//      0 = A f32 (cvt in staging, drain loop).
// MODE: 0 INIT  u1=h@W1+b1: u1b=v, t1dst=tanh(v)
//       1 G1    u2=u1+.5dt(acc+c2): t1dst=tanh(u2), T:=reread(aux)+2*tanh
//       2 G2    u3=...: t1dst=tanh(u3), T+=2*tanh
//       3 G3    u4=u1+dt(acc+c2): T+=tanh(u4)
//       4 G4    u1'=u1+(dt/6)acc+dt*c2: u1b, t1dst=tanh, S (+)= (dt/6)*aux
//       5 ZFIN  z=h(aux)+acc+(t19-t0)*b2: t1dst=bf16(z)
//       6 WT    W21T[col*1024+row]=bf16(acc)   (builds W21^T)
//       7 OUT   outF=acc+bias
// ---------------------------------------------------------------------------
template <int MODE, int ADT>
__global__ __launch_bounds__(256, 4) void gemm_ode(
    const void* Av, const unsigned short* __restrict__ Bt,
    int N, int K,
    const float* __restrict__ bias, const float* __restrict__ tgrid,
    int step, int first,
    unsigned short* __restrict__ u1b,
    unsigned short* __restrict__ Tb,
    unsigned short* __restrict__ Sb,
    unsigned short* __restrict__ t1dst,
    const void* aux,
    const float* __restrict__ c2,
    float* __restrict__ outF) {
  __shared__ short8 AsV[2][512];  // 64 rows x 8 swizzled chunks x 16B
  __shared__ short8 BsV[2][512];

  const int t = threadIdx.x;
  int bx = blockIdx.x, by = blockIdx.y;
  // Bijective XCD stripe swizzle for (16,64): XCD x = lin&7 owns by in
  // [x*8, x*8+8). Working set/XCD: A 1MB + B 2MB = 3MB < 4MB L2.
  if (gridDim.x == 16 && gridDim.y == 64) {
    const int lin = bx + (by << 4);
    const int x = lin & 7, j = lin >> 3;  // j in 0..127
    bx = j & 15;
    by = (x << 3) | (j >> 4);
  }
  const int mBase = by * 64, nBase = bx * 64;
  const int wave = t >> 6, lane = t & 63;
  const int wr = wave >> 1, wc = wave & 1;
  const int q = lane >> 4, m16 = lane & 15;

  float4v acc[2][2];
#pragma unroll
  for (int r = 0; r < 2; ++r)
#pragma unroll
    for (int c = 0; c < 2; ++c) acc[r][c] = (float4v){0.f, 0.f, 0.f, 0.f};

  const int r0 = t >> 3;               // staging row 0..31 (also row+32)
  const int kcl = (t & 7) ^ (r0 & 7);  // swizzled k-chunk; (r0+32)&7==r0&7
  const unsigned short* aU = (const unsigned short*)Av + (size_t)(mBase + r0) * K + kcl * 8;
  const float* aF = (const float*)Av + (size_t)(mBase + r0) * K + kcl * 8;
  const unsigned short* bG = Bt + (size_t)(nBase + r0) * K + kcl * 8;

  auto computeT = [&](int buf) {
#pragma unroll
    for (int kk = 0; kk < 2; ++kk) {
      const int kc = kk * 4 + q;
      short8 af[2], bfr[2];
#pragma unroll
      for (int r = 0; r < 2; ++r) {
        const int arow = wr * 32 + r * 16 + m16;
        af[r] = AsV[buf][arow * 8 + (kc ^ (arow & 7))];
        const int brow = wc * 32 + r * 16 + m16;
        bfr[r] = BsV[buf][brow * 8 + (kc ^ (brow & 7))];
      }
#pragma unroll
      for (int r = 0; r < 2; ++r)
#pragma unroll
        for (int c = 0; c < 2; ++c)
          acc[r][c] = __builtin_amdgcn_mfma_f32_16x16x32_bf16(af[r], bfr[c],
                                                              acc[r][c], 0, 0, 0);
    }
  };

  if constexpr (ADT == 1) {
    auto stageT = [&](int buf, int k0) {
      load16(aU + k0, &AsV[buf][t]);
      load16(aU + (size_t)32 * K + k0, &AsV[buf][t + 256]);
      load16(bG + k0, &BsV[buf][t]);
      load16(bG + (size_t)32 * K + k0, &BsV[buf][t + 256]);
    };
    stageT(0, 0);
    int cur = 0;
    for (int k0 = BK; k0 < K; k0 += BK) {
      stageT(cur ^ 1, k0);  // next tile's 4 loads join the queue
      asm volatile("s_waitcnt vmcnt(4)" ::: "memory");
      __builtin_amdgcn_sched_barrier(0);
      __builtin_amdgcn_s_barrier();
      __builtin_amdgcn_sched_barrier(0);
      computeT(cur);
      asm volatile("s_waitcnt lgkmcnt(0)" ::: "memory");
      __builtin_amdgcn_sched_barrier(0);
      __builtin_amdgcn_s_barrier();
      __builtin_amdgcn_sched_barrier(0);
      cur ^= 1;
    }
    asm volatile("s_waitcnt vmcnt(0)" ::: "memory");
    __builtin_amdgcn_sched_barrier(0);
    __builtin_amdgcn_s_barrier();
    __builtin_amdgcn_sched_barrier(0);
    computeT(cur);
  } else {
    for (int k0 = 0; k0 < K; k0 += BK) {
      AsV[0][t] = packbf8(aF + k0);
      AsV[0][t + 256] = packbf8(aF + (size_t)32 * K + k0);
      load16(bG + k0, &BsV[0][t]);
      load16(bG + (size_t)32 * K + k0, &BsV[0][t + 256]);
      __builtin_amdgcn_s_waitcnt(0);
      __syncthreads();
      computeT(0);
      __syncthreads();
    }
  }

  // ---- fused epilogue ----
  float dtv = 0.f;
  if constexpr (MODE >= 1 && MODE <= 4) dtv = vsub_uniform(tgrid[step + 1], tgrid[step]);
  if constexpr (MODE == 5) dtv = vsub_uniform(tgrid[step], tgrid[0]);

  const int colBase = nBase + wc * 32 + m16;
  const int rowBase = mBase + wr * 32 + q * 4;
#pragma unroll
  for (int r = 0; r < 2; ++r) {
#pragma unroll
    for (int c = 0; c < 2; ++c) {
      const int col = colBase + c * 16;
#pragma unroll
      for (int e = 0; e < 4; ++e) {
        const int row = rowBase + r * 16 + e;
        const size_t idx = (size_t)row * N + col;
        const float v = acc[r][c][e];
        if constexpr (MODE == 0) {
          const float u1 = v + bias[col];
          u1b[idx] = f2bf(u1);
          t1dst[idx] = f2bf(tanhf(u1));
        } else if constexpr (MODE == 1) {
          const float u2 = bf2f(u1b[idx]) + 0.5f * dtv * (v + c2[col]);
          const float th = tanhf(u2);
          t1dst[idx] = f2bf(th);
          Tb[idx] = f2bf(bf2f(((const unsigned short*)aux)[idx]) + 2.f * th);
        } else if constexpr (MODE == 2) {
          const float u3 = bf2f(u1b[idx]) + 0.5f * dtv * (v + c2[col]);
          const float th = tanhf(u3);
          t1dst[idx] = f2bf(th);
          Tb[idx] = f2bf(bf2f(Tb[idx]) + 2.f * th);
        } else if constexpr (MODE == 3) {
          const float u4 = bf2f(u1b[idx]) + dtv * (v + c2[col]);
          Tb[idx] = f2bf(bf2f(Tb[idx]) + tanhf(u4));
        } else if constexpr (MODE == 4) {
          const float u1n = bf2f(u1b[idx]) + (dtv * (1.f / 6.f)) * v + dtv * c2[col];
          u1b[idx] = f2bf(u1n);
          t1dst[idx] = f2bf(tanhf(u1n));
          const float sOld = first ? 0.f : bf2f(Sb[idx]);
          Sb[idx] = f2bf(sOld + (dtv * (1.f / 6.f)) *
                                    bf2f(((const unsigned short*)aux)[idx]));
        } else if constexpr (MODE == 5) {
          const float z = ((const float*)aux)[idx] + v + dtv * bias[col];
          t1dst[idx] = f2bf(z);
        } else if constexpr (MODE == 6) {
          t1dst[(size_t)col * 1024 + row] = f2bf(v);
        } else {  // MODE 7: out projection
          outF[idx] = v + bias[col];
        }
      }
    }
  }
}

// ---------------------------------------------------------------------------
// Fused gate + c_tilde dual GEMM, 64x64 tiles, 4 blocks/CU, PIPELINED (R15):
// A-side prefetched into registers one K-tile ahead (x/h f32 + zB bf16,
// uniform 6 loads), Bs (WiT) double-buffered via global_load_lds; counted
// vmcnt(8). AsG/AsC single-buffered (2 barriers/step). LDS 32 KB.
// accG = [x|h]@WiT^T, accC = [x|z]@WiT^T; epilogue -> h_new, c_new.
// Numerics bit-identical to the R12 drain version (same pack rounding).
// ---------------------------------------------------------------------------
__global__ __launch_bounds__(256, 4) void gemm_fused(
    const float* __restrict__ x, const float* __restrict__ h,
    const unsigned short* __restrict__ zB,
    const unsigned short* __restrict__ WiT,  // 1024 x 1280 bf16
    const float* __restrict__ bi, const float* __restrict__ c_in,
    float* __restrict__ hnewF, float* __restrict__ cnewF) {
  __shared__ short8 AsG[512];
  __shared__ short8 AsC[512];
  __shared__ short8 Bs[2][512];

  const int t = threadIdx.x;
  int bx = blockIdx.x, by = blockIdx.y;
  {
    const int lin = bx + (by << 4);
    const int xc = lin & 7, j = lin >> 3;
    bx = j & 15;
    by = (xc << 3) | (j >> 4);
  }
  const int mBase = by * 64, nBase = bx * 64;
  const int wave = t >> 6, lane = t & 63;
  const int wr = wave >> 1, wc = wave & 1;
  const int q = lane >> 4, m16 = lane & 15;

  float4v accG[2][2], accC[2][2];
#pragma unroll
  for (int r = 0; r < 2; ++r)
#pragma unroll
    for (int c = 0; c < 2; ++c) {
      accG[r][c] = (float4v){0.f, 0.f, 0.f, 0.f};
      accC[r][c] = (float4v){0.f, 0.f, 0.f, 0.f};
    }

  const int r0 = t >> 3;
  const int kcl = (t & 7) ^ (r0 & 7);
  const int row0 = mBase + r0, row1 = row0 + 32;

  struct Regs { float4v a0, a1, a2, a3; short8 z0, z1; };
  Regs Ra, Rb;

  // Issue next tile's A-side loads into registers (6 loads, uniform count:
  // for isX tiles the z slots are dummy in-bounds reads of x, unused).
  auto issueA = [&](int i, Regs& R) {
    const int k0 = i * 64;
    if (k0 < 256) {
      const float* g0 = x + (size_t)row0 * 256 + k0 + kcl * 8;
      const float* g1 = x + (size_t)row1 * 256 + k0 + kcl * 8;
      R.a0 = *(const float4v*)g0; R.a1 = *(const float4v*)(g0 + 4);
      R.a2 = *(const float4v*)g1; R.a3 = *(const float4v*)(g1 + 4);
      R.z0 = *(const short8*)(const void*)g0;  // dummy, keeps vmcnt uniform
      R.z1 = *(const short8*)(const void*)g1;
    } else {
      const size_t o0 = (size_t)row0 * 1024 + (k0 - 256) + kcl * 8;
      const size_t o1 = (size_t)row1 * 1024 + (k0 - 256) + kcl * 8;
      R.a0 = *(const float4v*)(h + o0); R.a1 = *(const float4v*)(h + o0 + 4);
      R.a2 = *(const float4v*)(h + o1); R.a3 = *(const float4v*)(h + o1 + 4);
      R.z0 = *(const short8*)(zB + o0);
      R.z1 = *(const short8*)(zB + o1);
    }
  };
  auto issueB = [&](int i, int buf) {
    const int k0 = i * 64;
    load16(WiT + (size_t)(nBase + r0) * 1280 + k0 + kcl * 8, &Bs[buf][t]);
    load16(WiT + (size_t)(nBase + r0 + 32) * 1280 + k0 + kcl * 8,
           &Bs[buf][t + 256]);
  };
  auto computeF = [&](int buf) {
#pragma unroll
    for (int kk = 0; kk < 2; ++kk) {
      const int kc = kk * 4 + q;
      short8 ag[2], ac[2], bfr[2];
#pragma unroll
      for (int r = 0; r < 2; ++r) {
        const int arow = wr * 32 + r * 16 + m16;
        ag[r] = AsG[arow * 8 + (kc ^ (arow & 7))];
        ac[r] = AsC[arow * 8 + (kc ^ (arow & 7))];
        const int brow = wc * 32 + r * 16 + m16;
        bfr[r] = Bs[buf][brow * 8 + (kc ^ (brow & 7))];
      }
#pragma unroll
      for (int r = 0; r < 2; ++r)
#pragma unroll
        for (int c = 0; c < 2; ++c) {
          accG[r][c] = __builtin_amdgcn_mfma_f32_16x16x32_bf16(ag[r], bfr[c],
                                                               accG[r][c], 0, 0, 0);
          accC[r][c] = __builtin_amdgcn_mfma_f32_16x16x32_bf16(ac[r], bfr[c],
                                                               accC[r][c], 0, 0, 0);
        }
    }
  };

  int buf = 0;
  auto stepF = [&](int i, Regs& Rc, Regs& Rn) {
    if (i + 1 < 20) {
      issueA(i + 1, Rn);
      issueB(i + 1, buf ^ 1);
      asm volatile("s_waitcnt vmcnt(8)" ::: "memory");  // tile i's 8 done
    } else {
      asm volatile("s_waitcnt vmcnt(0)" ::: "memory");
    }
    __builtin_amdgcn_sched_barrier(0);
    // pack & write AsG/AsC from registers (same rounding as packbf8)
    {
      const bool isX = (i * 64) < 256;
      const short8 s0 = pack2(Rc.a0, Rc.a1);
      const short8 s1 = pack2(Rc.a2, Rc.a3);
      AsG[t] = s0;
      AsG[t + 256] = s1;
      AsC[t] = isX ? s0 : Rc.z0;
      AsC[t + 256] = isX ? s1 : Rc.z1;
    }
    asm volatile("s_waitcnt lgkmcnt(0)" ::: "memory");
    __builtin_amdgcn_sched_barrier(0);
    __builtin_amdgcn_s_barrier();
    __builtin_amdgcn_sched_barrier(0);
    computeF(buf);
    asm volatile("s_waitcnt lgkmcnt(0)" ::: "memory");
    __builtin_amdgcn_sched_barrier(0);
    __builtin_amdgcn_s_barrier();  // all waves done reading As/Bs[buf]
    __builtin_amdgcn_sched_barrier(0);
    buf ^= 1;
  };

  issueA(0, Ra);
  issueB(0, 0);
#pragma unroll 1
  for (int ii = 0; ii < 20; ii += 2) {
    stepF(ii, Ra, Rb);
    stepF(ii + 1, Rb, Ra);
  }

  const int colBase = nBase + wc * 32 + m16;
  const int rowBase = mBase + wr * 32 + q * 4;
#pragma unroll
  for (int r = 0; r < 2; ++r) {
#pragma unroll
    for (int c = 0; c < 2; ++c) {
      const int col = colBase + c * 16;
      const float bv = bi[col];
#pragma unroll
      for (int e = 0; e < 4; ++e) {
        const int row = rowBase + r * 16 + e;
        const size_t idx = (size_t)row * 1024 + col;
        const float g = 1.f / (1.f + expf(-(accG[r][c][e] + bv)));
        const float ct = 1.f / (1.f + expf(-(accC[r][c][e] + bv)));
        const float cn = g * (c_in[idx] + ct);
        const float hn = g * tanhf(cn);
        hnewF[idx] = hn;
        cnewF[idx] = cn;
      }
    }
  }
}

// out[c][r] = bf16(in[r][c]); in f32 RxC. block (32,8), grid (C/32, R/32).
__global__ __launch_bounds__(256) void transpose_f32_bf16(
    const float* __restrict__ in, unsigned short* __restrict__ out,
    int R, int C) {
  __shared__ float tile[32][33];
  const int c0 = blockIdx.x * 32, r0 = blockIdx.y * 32;
  const int tx = threadIdx.x, ty = threadIdx.y;
#pragma unroll
  for (int i = 0; i < 32; i += 8)
    tile[ty + i][tx] = in[(size_t)(r0 + ty + i) * C + c0 + tx];
  __syncthreads();
#pragma unroll
  for (int i = 0; i < 32; i += 8)
    out[(size_t)(c0 + ty + i) * R + r0 + tx] = f2bf(tile[tx][ty + i]);
}

// c2[n] = sum_k b2[k] * W1[k,n]  (1024-dot per thread; one-off, tiny)
__global__ __launch_bounds__(256) void c2_gemv(
    const float* __restrict__ b2, const float* __restrict__ W1,
    float* __restrict__ c2v) {
  const int n = blockIdx.x * 256 + threadIdx.x;
  float a = 0.f;
  for (int k = 0; k < 1024; ++k) a += b2[k] * W1[(size_t)k * 1024 + n];
  c2v[n] = a;
}

extern "C" void kernel_launch(void* const* d_in, const int* in_sizes, int n_in,
                              void* d_out, int out_size, void* d_ws, size_t ws_size,
                              hipStream_t stream) {
  const float* x  = (const float*)d_in[0];   // 4096x256
  const float* h  = (const float*)d_in[1];   // 4096x1024
  const float* c  = (const float*)d_in[2];   // 4096x1024
  const float* t  = (const float*)d_in[3];   // 20
  const float* Wi = (const float*)d_in[4];   // 1280x1024
  const float* bi = (const float*)d_in[5];   // 1024
  const float* Wo = (const float*)d_in[6];   // 1024x256
  const float* bo = (const float*)d_in[7];   // 256
  const float* W1 = (const float*)d_in[8];   // 1024x1024
  const float* b1 = (const float*)d_in[9];   // 1024
  const float* W2 = (const float*)d_in[10];  // 1024x1024
  const float* b2 = (const float*)d_in[11];  // 1024

  const size_t MB = 1ull << 20;
  char* ws = (char*)d_ws;
  unsigned short* W21T = (unsigned short*)(ws);                      // [0,2M)
  unsigned short* W2T  = (unsigned short*)(ws + 2 * MB);             // [2,4M)
  unsigned short* WiT  = (unsigned short*)(ws + 4 * MB);             // [4,6.5M)
  unsigned short* WoT  = (unsigned short*)(ws + 6 * MB + 512 * 1024);// [6.5,7M)
  unsigned short* P0   = (unsigned short*)(ws + 7 * MB);             // [7,15M)

  // d_out overlays (all dead before the final output writes)
  float*          outF  = (float*)d_out;
  float*          hnewF = outF + 1048576;                            // [4,20M)
  float*          cnewF = outF + 5242880;                            // [20,36M)
  unsigned short* u1b   = (unsigned short*)d_out;                    // [0,8M)
  unsigned short* Tb    = (unsigned short*)((char*)d_out + 8 * MB);  // [8,16M)
  unsigned short* P1    = (unsigned short*)((char*)d_out + 16 * MB); // [16,24M)
  unsigned short* Sb    = (unsigned short*)((char*)d_out + 24 * MB); // [24,32M)
  unsigned short* W1T   = (unsigned short*)((char*)d_out + 32 * MB); // [32,34M)
  float*          c2v   = (float*)((char*)d_out + 34 * MB);          // 4 KB

  const dim3 tb(32, 8), blk(256), g(16, 64);

  // weight prep
  transpose_f32_bf16<<<dim3(32, 32), tb, 0, stream>>>(W1, W1T, 1024, 1024);
  transpose_f32_bf16<<<dim3(32, 32), tb, 0, stream>>>(W2, W2T, 1024, 1024);
  transpose_f32_bf16<<<dim3(32, 40), tb, 0, stream>>>(Wi, WiT, 1280, 1024);
  transpose_f32_bf16<<<dim3(8, 32),  tb, 0, stream>>>(Wo, WoT, 1024, 256);
  c2_gemv<<<4, blk, 0, stream>>>(b2, W1, c2v);
  // W21T = (W2@W1)^T
  gemm_ode<6, 0><<<dim3(16, 16), blk, 0, stream>>>(
      W2, W1T, 1024, 1024, b1, t, 0, 0,
      nullptr, nullptr, nullptr, W21T, nullptr, nullptr, nullptr);
  // u1 = h@W1 + b1 ; t1_1 = tanh(u1) -> P0
  gemm_ode<0, 0><<<g, blk, 0, stream>>>(
      h, W1T, 1024, 1024, b1, t, 0, 0,
      u1b, nullptr, nullptr, P0, nullptr, nullptr, nullptr);

  // RK4: 19 steps x 4 single GEMMs (all vs W21T)
  for (int s = 0; s < 19; ++s) {
    gemm_ode<1, 1><<<g, blk, 0, stream>>>(
        P0, W21T, 1024, 1024, b1, t, s, 0,
        u1b, Tb, nullptr, P1, P0, c2v, nullptr);
    gemm_ode<2, 1><<<g, blk, 0, stream>>>(
        P1, W21T, 1024, 1024, b1, t, s, 0,
        u1b, Tb, nullptr, P0, nullptr, c2v, nullptr);
    gemm_ode<3, 1><<<g, blk, 0, stream>>>(
        P0, W21T, 1024, 1024, b1, t, s, 0,
        u1b, Tb, nullptr, nullptr, nullptr, c2v, nullptr);
    gemm_ode<4, 1><<<g, blk, 0, stream>>>(
        Tb, W21T, 1024, 1024, b1, t, s, (s == 0) ? 1 : 0,
        u1b, nullptr, Sb, P0, Tb, c2v, nullptr);
  }

  // z = h_ode = h + S@W2 + (t19-t0)*b2  -> bf16 into P0
  gemm_ode<5, 1><<<g, blk, 0, stream>>>(
      Sb, W2T, 1024, 1024, b2, t, 19, 0,
      nullptr, nullptr, nullptr, P0, h, nullptr, nullptr);

  // fused gate + c_tilde -> h_new, c_new (f32)
  gemm_fused<<<g, blk, 0, stream>>>(x, h, P0, WiT, bi, c, hnewF, cnewF);

  // out = h_new(f32) @ Wo + bo
  gemm_ode<7, 0><<<dim3(4, 64), blk, 0, stream>>>(
      hnewF, WoT, 256, 1024, bo, t, 0, 0,
      nullptr, nullptr, nullptr, nullptr, nullptr, nullptr, outF);
}